// Round 1
// baseline (2690.474 us; speedup 1.0000x reference)
//
#include <hip/hip_runtime.h>

// Problem constants
#define BB 2048   // batch
#define TT 128    // timesteps
#define VV 25     // input features
#define HH 512    // hidden
#define NC 100    // classes

typedef __attribute__((ext_vector_type(8))) _Float16 half8;
typedef __attribute__((ext_vector_type(4))) float f32x4;

__device__ __forceinline__ float fsigmoid(float x) { return 1.0f / (1.0f + __expf(-x)); }
__device__ __forceinline__ float ftanh(float x) {
    float e = __expf(2.0f * x);
    return 1.0f - 2.0f / (e + 1.0f);
}

// ---- prep: weights -> MFMA-fragment-native fp16 layout ----
// WT[kq][n] : 16B group = fp16(W[n][kq*8 .. kq*8+7])  (kq 0..63 = W_hh,
// 64..67 = W_ih zero-padded to K=32). B-frag load for K32 chunk cc:
// lane(col,quad) reads WT[cc*4+quad][n0+col] -> 4 x 256B segments.
__global__ __launch_bounds__(256) void prep_whh_t(const float* __restrict__ W,
                                                  _Float16* __restrict__ WT) {
    int i = blockIdx.x * 256 + threadIdx.x;   // 2048 n x 64 kq, grid 512
    int n = i & 2047, kq = i >> 11;
    half8 h8;
    #pragma unroll
    for (int j = 0; j < 8; ++j) h8[j] = (_Float16)W[(size_t)n * HH + kq * 8 + j];  // RNE cvt
    ((half8*)WT)[(size_t)kq * 2048 + n] = h8;
}

__global__ __launch_bounds__(256) void prep_wih_t(const float* __restrict__ W,
                                                  _Float16* __restrict__ WT) {
    int i = blockIdx.x * 256 + threadIdx.x;   // 2048 n x 4 kq, grid 32
    int n = i & 2047, kq4 = i >> 11;
    half8 h8;
    #pragma unroll
    for (int j = 0; j < 8; ++j) {
        int k = kq4 * 8 + j;
        h8[j] = (k < VV) ? (_Float16)W[(size_t)n * VV + k] : (_Float16)0.0f;
    }
    ((half8*)WT)[(size_t)(64 + kq4) * 2048 + n] = h8;
}

// One LSTM timestep — barrier-free / LDS-free rewrite of the r8 structure.
//
// Key observation: the A-fragment of mfma_f32_16x16x32_f16 (lane -> row =
// lane&15, k = quad*8..+7) is directly loadable from the fp16 h plane as a
// single half8: one wave-load touches 16 rows x 64B fully-utilized lines.
// The old LDS staging only shared A across wn-twin waves — L1 (same CU)
// provides that for free. Removing LDS removes all 8 per-step
// __syncthreads, whose s_waitcnt vmcnt(0) drains were flushing the B/A
// prefetch queue every K64 and serializing L2 latency 8x per step.
//
// Register pipeline: depth-4 slot ring (slot = chunk&3) on both A and B
// frags -> up to 24 loads in flight, consumed ~310 matrix-pipe cycles after
// issue (2 waves/SIMD x 8 MFMA x ~4.85cy x 4 chunks), covering L2 latency.
// x-tail msg f32 loads are issued in the prologue and converted to fp16 at
// chunk 12, so their L3 latency hides under the main loop.
//
// t==0 specialization: h is identically zero, so all 16 h-chunks are
// skipped and c is not read (cn = i*g) — this also removes the host-side
// memset of c/h0 entirely.
//
// Grid (32,16) = 512 blocks = 2 blocks/CU, 2 waves/SIMD, same tiling as
// before: wave w: wm=w&1 (32-batch half), wn=w>>1 (16-j half); wave tile
// 2 m-tiles x 4 gates of 16x16x32 f16. Launch-per-step remains the global
// barrier (r9/r11: in-kernel cross-XCD exchange costs more).
__global__ __launch_bounds__(256, 2) void lstm_step(
    const float* __restrict__ msg, int t,
    const _Float16* __restrict__ WT,
    const float* __restrict__ b_ih, const float* __restrict__ b_hh,
    const _Float16* __restrict__ hin, _Float16* __restrict__ hout,
    float* __restrict__ c)
{
    const int b0 = blockIdx.x * 64;
    const int j0 = blockIdx.y * 32;
    const int tid = threadIdx.x;
    const int lane = tid & 63;
    const int w = tid >> 6;
    const int wm = w & 1, wn = w >> 1;
    const int col = lane & 15, quad = lane >> 4;
    const int jj = j0 + wn * 16 + col;
    const bool first = (t == 0);

    f32x4 acc[2][4];   // [tm][gate]
    #pragma unroll
    for (int g = 0; g < 4; ++g) {
        float bias = b_ih[g * HH + jj] + b_hh[g * HH + jj];
        f32x4 bv = {bias, bias, bias, bias};
        acc[0][g] = bv;
        acc[1][g] = bv;
    }

    const half8* WT8 = (const half8*)WT;
    int bidx[4];
    #pragma unroll
    for (int g = 0; g < 4; ++g) bidx[g] = quad * 2048 + g * HH + jj;

    // A bases: row = b0 + wm*32 + tm*16 + col, k-offset quad*8 (16B aligned)
    const _Float16* aB[2];
    #pragma unroll
    for (int tm = 0; tm < 2; ++tm)
        aB[tm] = hin + (size_t)(b0 + wm * 32 + tm * 16 + col) * HH + quad * 8;

    // x-tail raw f32 loads (K=25 padded to 32), issued now, cvt at chunk 12
    float xv[2][8];
    #pragma unroll
    for (int tm = 0; tm < 2; ++tm) {
        const size_t mb = ((size_t)(b0 + wm * 32 + tm * 16 + col) * TT + t) * VV;
        #pragma unroll
        for (int j = 0; j < 8; ++j) {
            int k = quad * 8 + j;
            xv[tm][j] = (k < VV) ? msg[mb + k] : 0.0f;
        }
    }

    half8 Ah[4][2];    // [slot][tm]
    half8 Bs[4][4];    // [slot][gate]

    if (!first) {
        // prologue: chunks 0..3 into slots 0..3 (24 loads in flight)
        #pragma unroll
        for (int pc = 0; pc < 4; ++pc) {
            #pragma unroll
            for (int tm = 0; tm < 2; ++tm)
                Ah[pc][tm] = *(const half8*)(aB[tm] + pc * 32);
            #pragma unroll
            for (int g = 0; g < 4; ++g)
                Bs[pc][g] = WT8[pc * 8192 + bidx[g]];
        }
        #pragma unroll
        for (int cc = 0; cc < 16; ++cc) {
            const int sl = cc & 3;
            #pragma unroll
            for (int tm = 0; tm < 2; ++tm)
                #pragma unroll
                for (int g = 0; g < 4; ++g)
                    acc[tm][g] = __builtin_amdgcn_mfma_f32_16x16x32_f16(Ah[sl][tm], Bs[sl][g], acc[tm][g], 0, 0, 0);
            const int pf = cc + 4;                 // prefetch 4 chunks ahead
            if (pf < 16) {
                #pragma unroll
                for (int tm = 0; tm < 2; ++tm)
                    Ah[sl][tm] = *(const half8*)(aB[tm] + pf * 32);
                #pragma unroll
                for (int g = 0; g < 4; ++g)
                    Bs[sl][g] = WT8[pf * 8192 + bidx[g]];
            } else if (pf == 16) {
                // x-projection tail (chunk 16 = zero-padded W_ih): A from
                // the prologue's msg values, B from WT rows 64..67
                #pragma unroll
                for (int tm = 0; tm < 2; ++tm) {
                    half8 xh;
                    #pragma unroll
                    for (int j = 0; j < 8; ++j) xh[j] = (_Float16)xv[tm][j];
                    Ah[sl][tm] = xh;
                }
                #pragma unroll
                for (int g = 0; g < 4; ++g)
                    Bs[sl][g] = WT8[16 * 8192 + bidx[g]];
            }
        }
        // tail chunk sits in slot 16&3 == 0
        #pragma unroll
        for (int tm = 0; tm < 2; ++tm)
            #pragma unroll
            for (int g = 0; g < 4; ++g)
                acc[tm][g] = __builtin_amdgcn_mfma_f32_16x16x32_f16(Ah[0][tm], Bs[0][g], acc[tm][g], 0, 0, 0);
    } else {
        // t==0: h==0, x-projection only
        #pragma unroll
        for (int tm = 0; tm < 2; ++tm) {
            half8 xh;
            #pragma unroll
            for (int j = 0; j < 8; ++j) xh[j] = (_Float16)xv[tm][j];
            Ah[0][tm] = xh;
        }
        #pragma unroll
        for (int g = 0; g < 4; ++g)
            Bs[0][g] = WT8[16 * 8192 + bidx[g]];
        #pragma unroll
        for (int tm = 0; tm < 2; ++tm)
            #pragma unroll
            for (int g = 0; g < 4; ++g)
                acc[tm][g] = __builtin_amdgcn_mfma_f32_16x16x32_f16(Ah[0][tm], Bs[0][g], acc[tm][g], 0, 0, 0);
    }

    // ---- cell update; h written as a single fp16 plane ----
    // C/D layout: col=lane&15 (=n), row=quad*4+reg  [m89]
    #pragma unroll
    for (int tm = 0; tm < 2; ++tm) {
        #pragma unroll
        for (int reg = 0; reg < 4; ++reg) {
            int b = b0 + wm * 32 + tm * 16 + quad * 4 + reg;
            size_t idx = (size_t)b * HH + jj;
            float i_ = fsigmoid(acc[tm][0][reg]);
            float f_ = fsigmoid(acc[tm][1][reg]);
            float g_ = ftanh(acc[tm][2][reg]);
            float o_ = fsigmoid(acc[tm][3][reg]);
            float cn = i_ * g_;
            if (!first) cn = __builtin_fmaf(f_, c[idx], cn);
            c[idx] = cn;
            hout[idx] = (_Float16)(o_ * ftanh(cn));
        }
    }
}

// out[b, cls] = dot(h, W_fc[cls]) + b_fc[cls]. 4 rows/block.
__global__ __launch_bounds__(256) void fc_kernel(
    const _Float16* __restrict__ h, const float* __restrict__ W_fc,
    const float* __restrict__ b_fc, float* __restrict__ out)
{
    __shared__ float hs[4][HH];
    const int b0 = blockIdx.x * 4;
    for (int i = threadIdx.x; i < 4 * HH; i += 256) {
        int r = i >> 9, k = i & 511;
        hs[r][k] = (float)h[(size_t)(b0 + r) * HH + k];
    }
    __syncthreads();
    const int tid = threadIdx.x;
    if (tid < 2 * NC) {
        int r = tid / NC, cls = tid % NC;
        const float4* wv = (const float4*)(W_fc + (size_t)cls * HH);
        const float4* h0 = (const float4*)hs[r];
        const float4* h1 = (const float4*)hs[r + 2];
        float s0 = 0.0f, s1 = 0.0f;
        #pragma unroll 4
        for (int k = 0; k < HH / 4; ++k) {
            float4 ww = wv[k];
            float4 a0 = h0[k], a1 = h1[k];
            s0 += a0.x * ww.x + a0.y * ww.y + a0.z * ww.z + a0.w * ww.w;
            s1 += a1.x * ww.x + a1.y * ww.y + a1.z * ww.z + a1.w * ww.w;
        }
        out[(size_t)(b0 + r) * NC + cls] = s0 + b_fc[cls];
        out[(size_t)(b0 + r + 2) * NC + cls] = s1 + b_fc[cls];
    }
}

extern "C" void kernel_launch(void* const* d_in, const int* in_sizes, int n_in,
                              void* d_out, int out_size, void* d_ws, size_t ws_size,
                              hipStream_t stream) {
    const float* msg  = (const float*)d_in[0];
    const float* W_ih = (const float*)d_in[1];
    const float* W_hh = (const float*)d_in[2];
    const float* b_ih = (const float*)d_in[3];
    const float* b_hh = (const float*)d_in[4];
    const float* W_fc = (const float*)d_in[5];
    const float* b_fc = (const float*)d_in[6];
    float* out = (float*)d_out;

    // ws: c(4MB) | h0 h1 (fp16, 2MB ea) | WT (fp16, 2.23MB) = 10.2MB
    // No memset needed: t==0 step neither reads hin nor c.
    float*    c  = (float*)d_ws;
    _Float16* h0 = (_Float16*)(c + (size_t)BB * HH);
    _Float16* h1 = h0 + (size_t)BB * HH;
    _Float16* WT = h1 + (size_t)BB * HH;

    prep_whh_t<<<512, 256, 0, stream>>>(W_hh, WT);
    prep_wih_t<<<32, 256, 0, stream>>>(W_ih, WT);

    _Float16 *hin = h0, *hout = h1;
    for (int t = 0; t < TT; ++t) {
        lstm_step<<<dim3(BB / 64, HH / 32), 256, 0, stream>>>(
            msg, t, WT, b_ih, b_hh, hin, hout, c);
        _Float16* tmp = hin; hin = hout; hout = tmp;
    }
    fc_kernel<<<BB / 4, 256, 0, stream>>>(hin, W_fc, b_fc, out);
}

// Round 3
// 1649.671 us; speedup vs baseline: 1.6309x; 1.6309x over previous
//
#include <hip/hip_runtime.h>

// Problem constants
#define BB 2048   // batch
#define TT 128    // timesteps
#define VV 25     // input features
#define HH 512    // hidden
#define NC 100    // classes

typedef __attribute__((ext_vector_type(8))) _Float16 half8;
typedef __attribute__((ext_vector_type(4))) float f32x4;

__device__ __forceinline__ float fsigmoid(float x) { return 1.0f / (1.0f + __expf(-x)); }
__device__ __forceinline__ float ftanh(float x) {
    float e = __expf(2.0f * x);
    return 1.0f - 2.0f / (e + 1.0f);
}

// Workgroup barrier WITHOUT the vmcnt(0) drain __syncthreads() forces.
// Contract: all this wave's LDS ops complete (lgkmcnt(0)) before the
// barrier; global-load (vmcnt) prefetches stay in flight across it (T4).
// sched_barrier(0) right after the waitcnt pins the scheduler (guide rule
// #18: hipcc may hoist register-only ops past inline-asm waitcnt); memory
// clobbers pin LDS ops to their side of the barrier.
__device__ __forceinline__ void bar_nodrain() {
    asm volatile("s_waitcnt lgkmcnt(0)" ::: "memory");
    __builtin_amdgcn_sched_barrier(0);
    __builtin_amdgcn_s_barrier();
    asm volatile("" ::: "memory");
}

// ---- prep: weights -> MFMA-fragment-native fp16 layout ----
// WT[kq][n] : 16B group = fp16(W[n][kq*8 .. kq*8+7])  (kq 0..63 = W_hh,
// 64..67 = W_ih zero-padded to K=32). B-frag load for K32 chunk cc:
// lane(col,quad) reads WT[cc*4+quad][n0+col] -> 4 x 256B segments.
__global__ __launch_bounds__(256) void prep_whh_t(const float* __restrict__ W,
                                                  _Float16* __restrict__ WT) {
    int i = blockIdx.x * 256 + threadIdx.x;   // 2048 n x 64 kq, grid 512
    int n = i & 2047, kq = i >> 11;
    half8 h8;
    #pragma unroll
    for (int j = 0; j < 8; ++j) h8[j] = (_Float16)W[(size_t)n * HH + kq * 8 + j];  // RNE cvt
    ((half8*)WT)[(size_t)kq * 2048 + n] = h8;
}

__global__ __launch_bounds__(256) void prep_wih_t(const float* __restrict__ W,
                                                  _Float16* __restrict__ WT) {
    int i = blockIdx.x * 256 + threadIdx.x;   // 2048 n x 4 kq, grid 32
    int n = i & 2047, kq4 = i >> 11;
    half8 h8;
    #pragma unroll
    for (int j = 0; j < 8; ++j) {
        int k = kq4 * 8 + j;
        h8[j] = (k < VV) ? (_Float16)W[(size_t)n * VV + k] : (_Float16)0.0f;
    }
    ((half8*)WT)[(size_t)(64 + kq4) * 2048 + n] = h8;
}

// One LSTM timestep — proven r8 structure (LDS-staged A, register B) with
// three deltas vs the 1558us baseline:
//  1. bar_nodrain() instead of __syncthreads(): B prefetches are no longer
//     drained to vmcnt(0) at every K64 barrier (T4, counted waits stay
//     compiler-inserted and correct).
//  2. B ring deepened 2->4 slots (prefetch cc+4): B frags are ~2 K64
//     iterations old at first use, covering L2/L3 latency.
//  3. x-tail A-fragment built directly in registers (layout verified in
//     round 1) — drops the it==7 LDS staging and its barrier; c[] loads
//     hoisted ahead of the tail MFMAs.
// t==0 specialization (h==0: x-projection only, c not read) removes the
// host memset. Grid (32,16) = 512 blocks = 2 blocks/CU, 2 waves/SIMD.
// Wave w: wm=w&1 (32-batch half), wn=w>>1 (16-j half); wave tile 2 m-tiles
// x 4 gates of 16x16x32 f16. Launch-per-step remains the global barrier
// (r9/r11: in-kernel cross-XCD exchange costs more).
__global__ __launch_bounds__(256, 2) void lstm_step(
    const float* __restrict__ msg, int t,
    const _Float16* __restrict__ WT,
    const float* __restrict__ b_ih, const float* __restrict__ b_hh,
    const _Float16* __restrict__ hin, _Float16* __restrict__ hout,
    float* __restrict__ c)
{
    const int b0 = blockIdx.x * 64;
    const int j0 = blockIdx.y * 32;
    const int tid = threadIdx.x;
    const int lane = tid & 63;
    const int w = tid >> 6;
    const int wm = w & 1, wn = w >> 1;
    const int col = lane & 15, quad = lane >> 4;
    const int jj = j0 + wn * 16 + col;
    const bool first = (t == 0);

    // [buf][row][k]; row stride 72 halves (144B, 16B-aligned): frag b128
    // reads conflict-free. 18.4 KB total.
    __shared__ _Float16 Abuf[2][64][72];

    f32x4 acc[2][4];   // [tm][gate]
    #pragma unroll
    for (int g = 0; g < 4; ++g) {
        float bias = b_ih[g * HH + jj] + b_hh[g * HH + jj];
        f32x4 bv = {bias, bias, bias, bias};
        acc[0][g] = bv;
        acc[1][g] = bv;
    }

    // A staging: 64 rows x 64 k / 256 thr -> 16 halves (2 x half8) each.
    const int arow = tid >> 2, aseg = (tid & 3) << 4;
    const _Float16* aph = hin + (size_t)(b0 + arow) * HH + aseg;

    const half8* WT8 = (const half8*)WT;
    int bidx[4];
    #pragma unroll
    for (int g = 0; g < 4; ++g) bidx[g] = quad * 2048 + g * HH + jj;

    half8 Bs[4][4];        // B ring, depth 4 (slot = chunk & 3)
    half8 ra[2];           // staged A regs (next K64 chunk)
    float xv[2][8];        // x-tail A-fragment values (loaded at it==6)

    if (!first) {
        // ---- prologue: A chunk0 -> LDS buf0; chunk1 -> ra; B chunks 0..3 ----
        ra[0] = *(const half8*)(aph);
        ra[1] = *(const half8*)(aph + 8);
        #pragma unroll
        for (int pc = 0; pc < 4; ++pc)
            #pragma unroll
            for (int g = 0; g < 4; ++g) Bs[pc][g] = WT8[pc * 8192 + bidx[g]];
        *(half8*)&Abuf[0][arow][aseg]     = ra[0];   // counted vmcnt wait (ra only)
        *(half8*)&Abuf[0][arow][aseg + 8] = ra[1];
        ra[0] = *(const half8*)(aph + 64);
        ra[1] = *(const half8*)(aph + 72);
        bar_nodrain();

        #pragma unroll
        for (int it = 0; it < 8; ++it) {
            const int buf = it & 1;
            #pragma unroll
            for (int kk = 0; kk < 2; ++kk) {
                const int cc = it * 2 + kk;      // K32 chunk 0..15
                const int sl = cc & 3;
                half8 ahf[2];
                #pragma unroll
                for (int tm = 0; tm < 2; ++tm)
                    ahf[tm] = *(const half8*)&Abuf[buf][wm * 32 + tm * 16 + col][kk * 32 + quad * 8];
                #pragma unroll
                for (int tm = 0; tm < 2; ++tm)
                    #pragma unroll
                    for (int g = 0; g < 4; ++g)
                        acc[tm][g] = __builtin_amdgcn_mfma_f32_16x16x32_f16(ahf[tm], Bs[sl][g], acc[tm][g], 0, 0, 0);
                // prefetch B chunk+4 into the slot just consumed (16 = Wih tail)
                const int pf = cc + 4;
                if (pf <= 16) {
                    #pragma unroll
                    for (int g = 0; g < 4; ++g) Bs[sl][g] = WT8[pf * 8192 + bidx[g]];
                }
            }
            if (it < 7) {
                *(half8*)&Abuf[buf ^ 1][arow][aseg]     = ra[0];   // ra = K64 chunk it+1
                *(half8*)&Abuf[buf ^ 1][arow][aseg + 8] = ra[1];
                if (it < 6) {
                    const int kt = (it + 2) * 64;
                    ra[0] = *(const half8*)(aph + kt);
                    ra[1] = *(const half8*)(aph + kt + 8);
                } else {
                    // it==6: x-tail loads, direct A-fragment layout
                    // (row = wm*32 + tm*16 + col, k = quad*8 + j; K=25 pad 32)
                    #pragma unroll
                    for (int tm = 0; tm < 2; ++tm) {
                        const size_t mb = ((size_t)(b0 + wm * 32 + tm * 16 + col) * TT + t) * VV;
                        #pragma unroll
                        for (int j = 0; j < 8; ++j) {
                            int k = quad * 8 + j;
                            xv[tm][j] = (k < VV) ? msg[mb + k] : 0.0f;
                        }
                    }
                }
                bar_nodrain();       // it==7: no staging -> no barrier needed
            }
        }
    } else {
        // t==0: h==0 -> x-projection only
        #pragma unroll
        for (int tm = 0; tm < 2; ++tm) {
            const size_t mb = ((size_t)(b0 + wm * 32 + tm * 16 + col) * TT + t) * VV;
            #pragma unroll
            for (int j = 0; j < 8; ++j) {
                int k = quad * 8 + j;
                xv[tm][j] = (k < VV) ? msg[mb + k] : 0.0f;
            }
        }
        #pragma unroll
        for (int g = 0; g < 4; ++g) Bs[0][g] = WT8[16 * 8192 + bidx[g]];
    }

    // ---- hoist c loads ahead of the tail MFMAs (hide L2/L3 latency) ----
    float cv[2][4];
    if (!first) {
        #pragma unroll
        for (int tm = 0; tm < 2; ++tm)
            #pragma unroll
            for (int reg = 0; reg < 4; ++reg) {
                int b = b0 + wm * 32 + tm * 16 + quad * 4 + reg;
                cv[tm][reg] = c[(size_t)b * HH + jj];
            }
    }

    // ---- x-projection tail: chunk 16 (K=32), B slot 16&3 == 0 ----
    {
        half8 ahf[2];
        #pragma unroll
        for (int tm = 0; tm < 2; ++tm) {
            half8 xh;
            #pragma unroll
            for (int j = 0; j < 8; ++j) xh[j] = (_Float16)xv[tm][j];
            ahf[tm] = xh;
        }
        #pragma unroll
        for (int tm = 0; tm < 2; ++tm)
            #pragma unroll
            for (int g = 0; g < 4; ++g)
                acc[tm][g] = __builtin_amdgcn_mfma_f32_16x16x32_f16(ahf[tm], Bs[0][g], acc[tm][g], 0, 0, 0);
    }

    // ---- cell update; h written as a single fp16 plane ----
    // C/D layout: col=lane&15 (=n), row=quad*4+reg  [m89]
    #pragma unroll
    for (int tm = 0; tm < 2; ++tm) {
        #pragma unroll
        for (int reg = 0; reg < 4; ++reg) {
            int b = b0 + wm * 32 + tm * 16 + quad * 4 + reg;
            size_t idx = (size_t)b * HH + jj;
            float i_ = fsigmoid(acc[tm][0][reg]);
            float f_ = fsigmoid(acc[tm][1][reg]);
            float g_ = ftanh(acc[tm][2][reg]);
            float o_ = fsigmoid(acc[tm][3][reg]);
            float cn = i_ * g_;
            if (!first) cn = __builtin_fmaf(f_, cv[tm][reg], cn);
            c[idx] = cn;
            hout[idx] = (_Float16)(o_ * ftanh(cn));
        }
    }
}

// out[b, cls] = dot(h, W_fc[cls]) + b_fc[cls]. 4 rows/block.
__global__ __launch_bounds__(256) void fc_kernel(
    const _Float16* __restrict__ h, const float* __restrict__ W_fc,
    const float* __restrict__ b_fc, float* __restrict__ out)
{
    __shared__ float hs[4][HH];
    const int b0 = blockIdx.x * 4;
    for (int i = threadIdx.x; i < 4 * HH; i += 256) {
        int r = i >> 9, k = i & 511;
        hs[r][k] = (float)h[(size_t)(b0 + r) * HH + k];
    }
    __syncthreads();
    const int tid = threadIdx.x;
    if (tid < 2 * NC) {
        int r = tid / NC, cls = tid % NC;
        const float4* wv = (const float4*)(W_fc + (size_t)cls * HH);
        const float4* h0 = (const float4*)hs[r];
        const float4* h1 = (const float4*)hs[r + 2];
        float s0 = 0.0f, s1 = 0.0f;
        #pragma unroll 4
        for (int k = 0; k < HH / 4; ++k) {
            float4 ww = wv[k];
            float4 a0 = h0[k], a1 = h1[k];
            s0 += a0.x * ww.x + a0.y * ww.y + a0.z * ww.z + a0.w * ww.w;
            s1 += a1.x * ww.x + a1.y * ww.y + a1.z * ww.z + a1.w * ww.w;
        }
        out[(size_t)(b0 + r) * NC + cls] = s0 + b_fc[cls];
        out[(size_t)(b0 + r + 2) * NC + cls] = s1 + b_fc[cls];
    }
}

extern "C" void kernel_launch(void* const* d_in, const int* in_sizes, int n_in,
                              void* d_out, int out_size, void* d_ws, size_t ws_size,
                              hipStream_t stream) {
    const float* msg  = (const float*)d_in[0];
    const float* W_ih = (const float*)d_in[1];
    const float* W_hh = (const float*)d_in[2];
    const float* b_ih = (const float*)d_in[3];
    const float* b_hh = (const float*)d_in[4];
    const float* W_fc = (const float*)d_in[5];
    const float* b_fc = (const float*)d_in[6];
    float* out = (float*)d_out;

    // ws: c(4MB) | h0 h1 (fp16, 2MB ea) | WT (fp16, 2.23MB) = 10.2MB
    // No memset needed: the t==0 step reads neither hin nor c.
    float*    c  = (float*)d_ws;
    _Float16* h0 = (_Float16*)(c + (size_t)BB * HH);
    _Float16* h1 = h0 + (size_t)BB * HH;
    _Float16* WT = h1 + (size_t)BB * HH;

    prep_whh_t<<<512, 256, 0, stream>>>(W_hh, WT);
    prep_wih_t<<<32, 256, 0, stream>>>(W_ih, WT);

    _Float16 *hin = h0, *hout = h1;
    for (int t = 0; t < TT; ++t) {
        lstm_step<<<dim3(BB / 64, HH / 32), 256, 0, stream>>>(
            msg, t, WT, b_ih, b_hh, hin, hout, c);
        _Float16* tmp = hin; hin = hout; hout = tmp;
    }
    fc_kernel<<<BB / 4, 256, 0, stream>>>(hin, W_fc, b_fc, out);
}